// Round 6
// baseline (285.673 us; speedup 1.0000x reference)
//
#include <hip/hip_runtime.h>
#include <stdint.h>

#define BATCH 64
#define CDIM  64
#define NPTS  1024
#define ODIM  128
#define KNN   49
#define KNNP  52      // padded knn row stride (16B-aligned: 52*4=208=16*13)
#define BNEPS 1e-5f

typedef __attribute__((ext_vector_type(8))) short bf16x8;   // 8 bf16 (4 VGPRs)
typedef __attribute__((ext_vector_type(4))) float f32x4;

// ---- workspace layout (bytes) ----
#define O_XF   0
#define SZ_XF  (BATCH*64*2*64*8*4)        // 16,777,216  bf16 hi/lo fragments
#define O_SQ   (O_XF + SZ_XF)
#define SZ_SQ  (BATCH*NPTS*4)             // 262,144    per-col squared norms
#define O_KNN  (O_SQ + SZ_SQ)
#define SZ_KNN (BATCH*NPTS*KNNP*4)        // 13,631,488 knn indices (padded)
#define O_Z    (O_KNN + SZ_KNN)
#define SZ_Z   (BATCH*NPTS*CDIM*4)        // 16,777,216 aggregated features
#define WS_NEED ((size_t)(O_Z + SZ_Z))    // 47,448,064

// out[b*O+o] = beta - gamma*mean*rsqrt(var+eps)   (BN constant of pooled mean)
__global__ void gcn_init(const float* __restrict__ gamma, const float* __restrict__ beta,
                         const float* __restrict__ rmean, const float* __restrict__ rvar,
                         float* __restrict__ out) {
    int i = blockIdx.x * 256 + threadIdx.x;
    if (i < BATCH * ODIM) {
        int o = i & (ODIM - 1);
        out[i] = beta[o] - gamma[o] * rmean[o] * rsqrtf(rvar[o] + BNEPS);
    }
}

// ======================= K0: bf16 hi/lo split + MFMA-fragment swizzle + sq ==============
__global__ __launch_bounds__(256) void k0_split(const float* __restrict__ X,
                                                uint32_t* __restrict__ XF,
                                                float* __restrict__ sq) {
    const int b    = blockIdx.x >> 4;
    const int t16  = (blockIdx.x & 15) * 4 + (threadIdx.x >> 6);
    const int lane = threadIdx.x & 63;
    const int n    = t16 * 16 + (lane & 15);
    const int cg   = lane >> 4;
    const float* Xb = X + (size_t)b * CDIM * NPTS;
    float s = 0.f;
    for (int ks = 0; ks < 2; ks++) {
        uint32_t hi[4], lo[4];
#pragma unroll
        for (int dj = 0; dj < 4; dj++) {
            uint32_t hw[2], lw[2];
#pragma unroll
            for (int e = 0; e < 2; e++) {
                int c = ks * 32 + cg * 8 + dj * 2 + e;
                float x = Xb[(size_t)c * NPTS + n];
                s += x * x;
                uint32_t u  = __float_as_uint(x);
                uint32_t hr = (u + 0x7FFFu + ((u >> 16) & 1u)) >> 16;   // RTNE bf16
                float    hf = __uint_as_float(hr << 16);
                uint32_t ul = __float_as_uint(x - hf);
                uint32_t lr = (ul + 0x7FFFu + ((ul >> 16) & 1u)) >> 16;
                hw[e] = hr; lw[e] = lr;
            }
            hi[dj] = hw[0] | (hw[1] << 16);
            lo[dj] = lw[0] | (lw[1] << 16);
        }
        size_t entry = ((size_t)(b * 64 + t16) * 2 + ks) * 64 + lane;
        uint32_t* p = XF + entry * 8;
        *(uint4*)p       = make_uint4(hi[0], hi[1], hi[2], hi[3]);
        *(uint4*)(p + 4) = make_uint4(lo[0], lo[1], lo[2], lo[3]);
    }
    s += __shfl_xor(s, 16, 64);
    s += __shfl_xor(s, 32, 64);
    if (lane < 16) sq[b * NPTS + n] = s;
}

// ======================= K1: MFMA Gram + 16-bit select (4-row ILP, scan emit) ===========
// 256 threads (4 waves), 16 rows/block. Wave w: gram col-tiles w*16..+15, then
// rows 4w..4w+3. Keys = top-16 bits of monotone map, packed 2 rows/uint (32 KB).
// Select: 4 interleaved ballot binary searches over [wave_min, max_of_lane_mins];
// emit via per-lane counts + one packed inclusive scan (no ballots, no popc-masks).
__global__ __launch_bounds__(256, 4) void k1_gram_select(const uint32_t* __restrict__ XF,
                                                         const float* __restrict__ sq,
                                                         int* __restrict__ knn) {
    __shared__ uint32_t s_pk[8 * 1024];              // 32 KB packed keys
    const int b    = blockIdx.x >> 6;
    const int rt   = blockIdx.x & 63;                // 16-row tile
    const int wave = threadIdx.x >> 6, lane = threadIdx.x & 63;
    const int q = lane >> 4, l15 = lane & 15;

    // A fragments (rows rt*16..+15), shared by all waves
    bf16x8 ahi[2], alo[2];
#pragma unroll
    for (int ks = 0; ks < 2; ks++) {
        const uint32_t* p = XF + (((size_t)(b * 64 + rt) * 2 + ks) * 64 + lane) * 8;
        ahi[ks] = *(const bf16x8*)p;
        alo[ks] = *(const bf16x8*)(p + 4);
    }
    const float* sqb = sq + b * NPTS;
    const int swq = (q & 1) << 4;

#pragma unroll
    for (int tt = 0; tt < 16; tt++) {                // wave's 16 col-tiles
        const int t16 = wave * 16 + tt;
        f32x4 acc = {0.f, 0.f, 0.f, 0.f};
#pragma unroll
        for (int ks = 0; ks < 2; ks++) {
            const uint32_t* p = XF + (((size_t)(b * 64 + t16) * 2 + ks) * 64 + lane) * 8;
            bf16x8 bhi = *(const bf16x8*)p;
            bf16x8 blo = *(const bf16x8*)(p + 4);
            acc = __builtin_amdgcn_mfma_f32_16x16x32_bf16(ahi[ks], bhi, acc, 0, 0, 0);
            acc = __builtin_amdgcn_mfma_f32_16x16x32_bf16(alo[ks], bhi, acc, 0, 0, 0);
            acc = __builtin_amdgcn_mfma_f32_16x16x32_bf16(ahi[ks], blo, acc, 0, 0, 0);
        }
        const int col  = t16 * 16 + l15;
        const float sqv = sqb[col];
        float d[4];
#pragma unroll
        for (int i = 0; i < 4; i++)                  // C layout: row=(lane>>4)*4+reg
            d[i] = fmaf(-2.f, acc[i], sqv);          // sq_r dropped (row-monotone)
        if (t16 == rt) {                             // wave-uniform diag tile: self=inf
#pragma unroll
            for (int i = 0; i < 4; i++)
                if (l15 == q * 4 + i) d[i] = __uint_as_float(0x7F800000u);
        }
        uint32_t key[4];
#pragma unroll
        for (int i = 0; i < 4; i++) {
            uint32_t u = __float_as_uint(d[i]);
            key[i] = u ^ (uint32_t)(((int)u >> 31) | 0x80000000);  // monotone map
        }
        // pack high halves: low16 = key[0]>>16, high16 = key[1]>>16
        uint32_t pk01 = __builtin_amdgcn_perm(key[1], key[0], 0x07060302);
        uint32_t pk23 = __builtin_amdgcn_perm(key[3], key[2], 0x07060302);
        s_pk[(2 * q) * 1024 + (col ^ swq)]     = pk01;   // pair p=2q  (rows 4q,4q+1)
        s_pk[(2 * q + 1) * 1024 + (col ^ swq)] = pk23;   // pair p=2q+1(rows 4q+2,4q+3)
    }
    __syncthreads();

    // ---- load this wave's 4 rows of keys ----
    uint32_t k[4][16];
    {
        const int swr = (wave & 1) << 4;
#pragma unroll
        for (int tt = 0; tt < 16; tt++) {
            uint32_t a  = s_pk[(2 * wave) * 1024 + ((tt * 64 + lane) ^ swr)];
            uint32_t bb = s_pk[(2 * wave + 1) * 1024 + ((tt * 64 + lane) ^ swr)];
            k[0][tt] = a & 0xFFFFu;  k[1][tt] = a >> 16;
            k[2][tt] = bb & 0xFFFFu; k[3][tt] = bb >> 16;
        }
    }

    // ---- bounds per row: lo = wave min, hi = max over lanes of lane-min ----
    uint32_t lo[4], hi[4];
    {
        uint32_t lmin[4];
#pragma unroll
        for (int r = 0; r < 4; r++) {
            uint32_t m = k[r][0];
#pragma unroll
            for (int tt = 1; tt < 16; tt++) m = k[r][tt] < m ? k[r][tt] : m;
            lmin[r] = m;
        }
#pragma unroll
        for (int r = 0; r < 4; r++) { lo[r] = lmin[r]; hi[r] = lmin[r]; }
#pragma unroll
        for (int off = 1; off < 64; off <<= 1) {
#pragma unroll
            for (int r = 0; r < 4; r++) {
                uint32_t a = (uint32_t)__shfl_xor((int)lo[r], off, 64);
                uint32_t m = (uint32_t)__shfl_xor((int)hi[r], off, 64);
                lo[r] = a < lo[r] ? a : lo[r];
                hi[r] = m > hi[r] ? m : hi[r];       // cnt(<=hi) >= 64 >= KNN
            }
        }
    }

    // ---- 4 interleaved exact binary searches (16-bit space) ----
    for (int it = 0; it < 16; it++) {
        bool act0 = lo[0] < hi[0], act1 = lo[1] < hi[1];
        bool act2 = lo[2] < hi[2], act3 = lo[3] < hi[3];
        if (!act0 && !act1 && !act2 && !act3) break;
        uint32_t mid[4];
        int cnt[4] = {0, 0, 0, 0};
#pragma unroll
        for (int r = 0; r < 4; r++) mid[r] = (lo[r] + hi[r]) >> 1;
#pragma unroll
        for (int tt = 0; tt < 16; tt++) {
            cnt[0] += __popcll(__ballot(k[0][tt] <= mid[0]));
            cnt[1] += __popcll(__ballot(k[1][tt] <= mid[1]));
            cnt[2] += __popcll(__ballot(k[2][tt] <= mid[2]));
            cnt[3] += __popcll(__ballot(k[3][tt] <= mid[3]));
        }
#pragma unroll
        for (int r = 0; r < 4; r++)
            if (lo[r] < hi[r]) {
                if (cnt[r] >= KNN) hi[r] = mid[r]; else lo[r] = mid[r] + 1;
            }
    }

    // ---- emit via packed scan (lt-count low16, eq-count high16) ----
#pragma unroll
    for (int r = 0; r < 4; r++) {
        const uint32_t vstar = lo[r];
        int loc_lt = 0, loc_eq = 0;
#pragma unroll
        for (int tt = 0; tt < 16; tt++) {
            loc_lt += (k[r][tt] < vstar);
            loc_eq += (k[r][tt] == vstar);
        }
        uint32_t v = (uint32_t)loc_lt | ((uint32_t)loc_eq << 16);
#pragma unroll
        for (int off = 1; off < 64; off <<= 1) {     // inclusive scan over lanes
            uint32_t u = (uint32_t)__shfl_up((int)v, off, 64);
            if (lane >= off) v += u;
        }
        uint32_t tot = (uint32_t)__shfl((int)v, 63, 64);
        const int total_lt = (int)(tot & 0xFFFFu);   // == cnt(< vstar) <= 48
        int p_lt = (int)(v & 0xFFFFu) - loc_lt;      // exclusive lt base
        int p_eq = total_lt + ((int)(v >> 16) - loc_eq);
        int* kout = knn + ((size_t)b * NPTS + rt * 16 + 4 * wave + r) * KNNP;
#pragma unroll
        for (int tt = 0; tt < 16; tt++) {
            bool islt = k[r][tt] < vstar;
            bool iseq = k[r][tt] == vstar;
            int pos = islt ? p_lt : p_eq;
            bool wv = islt || (iseq && p_eq < KNN);
            if (wv) kout[pos] = tt * 64 + lane;
            p_lt += islt; p_eq += iseq;
        }
    }
}

// ======================= K2a: neighbor aggregation -> z =================================
// 512 threads, blocks = (b, cg): X slice staged ONCE per block.
// lane = r2*16 + kb*4 + g : 4 rows per iteration, 2-step shuffle reduce over kb.
__global__ __launch_bounds__(512) void k2a_aggregate(const float* __restrict__ X,
                                                     const int* __restrict__ knn,
                                                     float* __restrict__ z) {
    __shared__ float XT[16 * 1024];                  // 64 KB, [n][16ch] quad-swizzled
    const int b = blockIdx.x >> 2, cg = blockIdx.x & 3;
    const int t = threadIdx.x;
    const float* Xb = X + ((size_t)b * CDIM + cg * 16) * NPTS;
#pragma unroll
    for (int nn = 0; nn < 2; nn++) {                 // stage 16 ch x 1024 cols transposed
        int n = nn * 512 + t;
#pragma unroll
        for (int g = 0; g < 4; g++) {
            float4 v;
            v.x = Xb[(size_t)(4 * g + 0) * NPTS + n];
            v.y = Xb[(size_t)(4 * g + 1) * NPTS + n];
            v.z = Xb[(size_t)(4 * g + 2) * NPTS + n];
            v.w = Xb[(size_t)(4 * g + 3) * NPTS + n];
            int qp = g ^ ((n >> 1) & 3);             // full 32-bank spread for b128
            *(float4*)&XT[n * 16 + qp * 4] = v;
        }
    }
    __syncthreads();
    const int wave = t >> 6, lane = t & 63;
    const int r2 = lane >> 4, kb = (lane >> 2) & 3, g = lane & 3;
    for (int rr = 0; rr < 32; rr++) {                // 128 rows per wave, 4 at a time
        const int row = wave * 128 + rr * 4 + r2;
        const int* kr = knn + ((size_t)b * NPTS + row) * KNNP;
        float4 s = {0.f, 0.f, 0.f, 0.f};
#pragma unroll
        for (int cs = 0; cs < 3; cs++) {             // aligned dwordx4 knn loads
            int4 j4 = *(const int4*)&kr[(kb + 4 * cs) * 4];
            int js[4] = {j4.x, j4.y, j4.z, j4.w};
#pragma unroll
            for (int e = 0; e < 4; e++) {
                int j = js[e];
                float4 v = *(const float4*)&XT[j * 16 + ((g ^ ((j >> 1) & 3)) << 2)];
                s.x += v.x; s.y += v.y; s.z += v.z; s.w += v.w;
            }
        }
        if (kb == 0) {                               // tail k = 48
            int j = kr[48];
            float4 v = *(const float4*)&XT[j * 16 + ((g ^ ((j >> 1) & 3)) << 2)];
            s.x += v.x; s.y += v.y; s.z += v.z; s.w += v.w;
        }
#pragma unroll
        for (int off = 4; off <= 8; off <<= 1) {     // reduce over kb (bits [3:2])
            s.x += __shfl_xor(s.x, off, 64);
            s.y += __shfl_xor(s.y, off, 64);
            s.z += __shfl_xor(s.z, off, 64);
            s.w += __shfl_xor(s.w, off, 64);
        }
        if (kb == 0)
            *(float4*)&z[((size_t)b * NPTS + row) * CDIM + cg * 16 + g * 4] = s;
    }
}

// ======================= K2b: z -> W,relu,BN,pool -> out ================================
__global__ __launch_bounds__(256) void k2b_gemm(const float* __restrict__ z,
                                                const float* __restrict__ W,
                                                const float* __restrict__ bias,
                                                const float* __restrict__ gamma,
                                                const float* __restrict__ rvar,
                                                float* __restrict__ out) {
    __shared__ __align__(16) float s_zz[128 * 64];   // 32 KB staged z tile
    __shared__ float s_red[2][256];
    const int b = blockIdx.x >> 3, nq = blockIdx.x & 7;
    const int t = threadIdx.x;
    const float* zb = z + ((size_t)b * NPTS + nq * 128) * CDIM;
#pragma unroll
    for (int qq = 0; qq < 8; qq++) {                 // coalesced float4 staging
        int e = qq * 256 + t;
        *(float4*)&s_zz[e * 4] = *(const float4*)&zb[e * 4];
    }
    __syncthreads();
    const int o2 = t & 63, h = t >> 6;               // o in {o2, o2+64}; 4 row-groups
    float4 w0[16], w1[16];
#pragma unroll
    for (int c4 = 0; c4 < 16; c4++) {
        w0[c4] = *(const float4*)&W[(size_t)o2 * CDIM + c4 * 4];
        w1[c4] = *(const float4*)&W[(size_t)(o2 + 64) * CDIM + c4 * 4];
    }
    const float b0 = bias[o2], b1 = bias[o2 + 64];
    float r0 = 0.f, r1 = 0.f;
    for (int r = 0; r < 32; r++) {
        const float* zr = &s_zz[(h * 32 + r) * 64];  // wave-uniform -> LDS broadcast
        float a0 = 0.f, a1 = 0.f;
#pragma unroll
        for (int c4 = 0; c4 < 16; c4++) {
            float4 zv = *(const float4*)&zr[c4 * 4];
            a0 += w0[c4].x * zv.x + w0[c4].y * zv.y + w0[c4].z * zv.z + w0[c4].w * zv.w;
            a1 += w1[c4].x * zv.x + w1[c4].y * zv.y + w1[c4].z * zv.z + w1[c4].w * zv.w;
        }
        r0 += fmaxf(a0 * (1.f / KNN) + b0, 0.f);
        r1 += fmaxf(a1 * (1.f / KNN) + b1, 0.f);
    }
    s_red[0][t] = r0; s_red[1][t] = r1;
    __syncthreads();
    if (t < 128) {
        const int oo = t & 63, which = t >> 6;
        const int o = which * 64 + oo;
        float sum = s_red[which][oo] + s_red[which][64 + oo] +
                    s_red[which][128 + oo] + s_red[which][192 + oo];
        float scale = gamma[o] * rsqrtf(rvar[o] + BNEPS) * (1.f / NPTS);
        atomicAdd(&out[b * ODIM + o], sum * scale);
    }
}

// ======================= Fallback: round-1 fused kernel (no workspace) ==================
#define RTILE 8
#define APAD  1028
#define WPAD  132
#define POOLF (64 * WPAD)

__global__ __launch_bounds__(256) void gcn_main(
    const float* __restrict__ X, const float* __restrict__ W,
    const float* __restrict__ bias, const float* __restrict__ gamma,
    const float* __restrict__ rvar, float* __restrict__ out)
{
    __shared__ __align__(16) float s_pool[POOLF];
    __shared__ __align__(16) float s_fstage[4][APAD];
    __shared__ int   s_knn[RTILE][KNN];
    __shared__ float s_z[RTILE][CDIM];

    const int t = threadIdx.x;
    const int b = blockIdx.x >> 7;
    const int rtile = blockIdx.x & 127;
    const int r0 = rtile * RTILE;
    const float* Xb = X + (size_t)b * CDIM * NPTS;

    float acc[RTILE][4];
    float sqv[4];
#pragma unroll
    for (int r = 0; r < RTILE; r++)
#pragma unroll
        for (int u = 0; u < 4; u++) acc[r][u] = 0.f;
#pragma unroll
    for (int u = 0; u < 4; u++) sqv[u] = 0.f;

    for (int ch = 0; ch < 16; ch++) {
        const int c0 = ch * 4;
#pragma unroll
        for (int cc = 0; cc < 4; cc++) {
            float4 v = *(const float4*)(Xb + (size_t)(c0 + cc) * NPTS + 4 * t);
            *(float4*)&s_fstage[cc][4 * t] = v;
        }
        __syncthreads();
#pragma unroll
        for (int cc = 0; cc < 4; cc++) {
            float4 bv4 = *(const float4*)&s_fstage[cc][4 * t];
            float bv[4] = {bv4.x, bv4.y, bv4.z, bv4.w};
#pragma unroll
            for (int u = 0; u < 4; u++) sqv[u] += bv[u] * bv[u];
            const float* arow = Xb + (size_t)(c0 + cc) * NPTS + r0;
            float4 a0 = *(const float4*)(arow);
            float4 a1 = *(const float4*)(arow + 4);
            float av[8] = {a0.x, a0.y, a0.z, a0.w, a1.x, a1.y, a1.z, a1.w};
#pragma unroll
            for (int r = 0; r < RTILE; r++)
#pragma unroll
                for (int u = 0; u < 4; u++) acc[r][u] += av[r] * bv[u];
        }
        __syncthreads();
    }

    float* s_dist = s_pool;
#pragma unroll
    for (int r = 0; r < RTILE; r++) {
        const int rG = r0 + r;
        float d[4];
#pragma unroll
        for (int u = 0; u < 4; u++) {
            float dd = sqv[u] - 2.f * acc[r][u];
            d[u] = (4 * t + u == rG) ? __uint_as_float(0x7F800000u) : dd;
        }
        *(float4*)&s_dist[r * NPTS + 4 * t] = make_float4(d[0], d[1], d[2], d[3]);
    }
    __syncthreads();

    const int wave = t >> 6, lane = t & 63;
    const unsigned long long ltmask = (1ull << lane) - 1ull;
    for (int rr = 0; rr < 2; rr++) {
        const int row = wave * 2 + rr;
        unsigned key[16];
#pragma unroll
        for (int tt = 0; tt < 16; tt++) {
            unsigned u = __float_as_uint(s_dist[row * NPTS + tt * 64 + lane]);
            key[tt] = (u & 0x80000000u) ? ~u : (u | 0x80000000u);
        }
        unsigned lo = 0u, hi = 0xFFFFFFFFu;
        while (lo < hi) {
            unsigned mid = lo + ((hi - lo) >> 1);
            int cnt = 0;
#pragma unroll
            for (int tt = 0; tt < 16; tt++)
                cnt += __popcll(__ballot(key[tt] <= mid));
            if (cnt >= KNN) hi = mid; else lo = mid + 1;
        }
        const unsigned v49 = lo;
        int cntless = 0;
#pragma unroll
        for (int tt = 0; tt < 16; tt++)
            cntless += __popcll(__ballot(key[tt] < v49));
        const int need = KNN - cntless;
        int base = 0, eqtaken = 0;
#pragma unroll
        for (int tt = 0; tt < 16; tt++) {
            bool islt = key[tt] < v49;
            bool iseq = key[tt] == v49;
            unsigned long long meq = __ballot(iseq);
            int eqrank = eqtaken + __popcll(meq & ltmask);
            bool sel = islt || (iseq && (eqrank < need));
            unsigned long long msel = __ballot(sel);
            if (sel) {
                int pos = base + __popcll(msel & ltmask);
                s_knn[row][pos] = tt * 64 + lane;
            }
            base    += __popcll(msel);
            eqtaken += __popcll(meq);
        }
    }
    __syncthreads();

    float* astage = s_pool;
    float* s_redf = (float*)s_fstage;
    const int ar = t >> 5, acc8 = (t & 31) >> 2, ks = t & 3;
    for (int c0 = 0; c0 < CDIM; c0 += 8) {
#pragma unroll
        for (int qq = 0; qq < 8; qq++) {
            int if4 = qq * 256 + t;
            int cc = if4 >> 8, j4 = if4 & 255;
            float4 v = *(const float4*)(Xb + (size_t)(c0 + cc) * NPTS + 4 * j4);
            *(float4*)&astage[cc * APAD + 4 * j4] = v;
        }
        __syncthreads();
        float partial = 0.f;
        for (int k = ks; k < KNN; k += 4)
            partial += astage[acc8 * APAD + s_knn[ar][k]];
        s_redf[t] = partial;
        __syncthreads();
        if (t < 64) {
            int r = t >> 3, cc = t & 7;
            int bi = r * 32 + cc * 4;
            s_z[r][c0 + cc] = s_redf[bi] + s_redf[bi + 1] + s_redf[bi + 2] + s_redf[bi + 3];
        }
        __syncthreads();
    }

    float* wt = s_pool;
#pragma unroll 4
    for (int qq = 0; qq < 32; qq++) {
        int e = qq * 256 + t;
        int o = e >> 6, c = e & 63;
        wt[c * WPAD + o] = W[e];
    }
    __syncthreads();
    const int o = t & 127, rg = t >> 7;
    float facc[4] = {0.f, 0.f, 0.f, 0.f};
    for (int c = 0; c < CDIM; c += 4) {
        float w0 = wt[(c + 0) * WPAD + o], w1 = wt[(c + 1) * WPAD + o];
        float w2 = wt[(c + 2) * WPAD + o], w3 = wt[(c + 3) * WPAD + o];
#pragma unroll
        for (int qq = 0; qq < 4; qq++) {
            float4 zv = *(const float4*)&s_z[rg * 4 + qq][c];
            facc[qq] += w0 * zv.x + w1 * zv.y + w2 * zv.z + w3 * zv.w;
        }
    }
    const float bo = bias[o];
    float rsum = 0.f;
#pragma unroll
    for (int qq = 0; qq < 4; qq++) {
        float f = facc[qq] * (1.f / KNN) + bo;
        rsum += fmaxf(f, 0.f);
    }
    s_redf[t] = rsum;
    __syncthreads();
    if (t < 128) {
        float scale = gamma[t] * rsqrtf(rvar[t] + BNEPS) * (1.f / NPTS);
        atomicAdd(&out[b * ODIM + t], (s_redf[t] + s_redf[t + 128]) * scale);
    }
}

extern "C" void kernel_launch(void* const* d_in, const int* in_sizes, int n_in,
                              void* d_out, int out_size, void* d_ws, size_t ws_size,
                              hipStream_t stream) {
    const float* X     = (const float*)d_in[0];
    const float* W     = (const float*)d_in[1];
    const float* bias  = (const float*)d_in[2];
    const float* gamma = (const float*)d_in[3];
    const float* beta  = (const float*)d_in[4];
    const float* rmean = (const float*)d_in[5];
    const float* rvar  = (const float*)d_in[6];
    float* out = (float*)d_out;

    gcn_init<<<(BATCH * ODIM + 255) / 256, 256, 0, stream>>>(gamma, beta, rmean, rvar, out);
    if (ws_size >= WS_NEED) {
        uint8_t* ws = (uint8_t*)d_ws;
        uint32_t* XF  = (uint32_t*)(ws + O_XF);
        float*    sqw = (float*)(ws + O_SQ);
        int*      knn = (int*)(ws + O_KNN);
        float*    zw  = (float*)(ws + O_Z);
        k0_split<<<BATCH * 16, 256, 0, stream>>>(X, XF, sqw);
        k1_gram_select<<<BATCH * 64, 256, 0, stream>>>(XF, sqw, knn);
        k2a_aggregate<<<BATCH * 4, 512, 0, stream>>>(X, knn, zw);
        k2b_gemm<<<BATCH * 8, 256, 0, stream>>>(zw, W, bias, gamma, rvar, out);
    } else {
        gcn_main<<<BATCH * (NPTS / RTILE), 256, 0, stream>>>(X, W, bias, gamma, rvar, out);
    }
}

// Round 8
// 273.024 us; speedup vs baseline: 1.0463x; 1.0463x over previous
//
#include <hip/hip_runtime.h>
#include <stdint.h>

#define BATCH 64
#define CDIM  64
#define NPTS  1024
#define ODIM  128
#define KNN   49
#define KNNP  52      // padded knn row stride (16B-aligned: 52*4=208=16*13)
#define BNEPS 1e-5f

typedef __attribute__((ext_vector_type(8))) short bf16x8;   // 8 bf16 (4 VGPRs)
typedef __attribute__((ext_vector_type(4))) float f32x4;

__device__ __forceinline__ int mbcnt64(unsigned long long m) {
    return __builtin_amdgcn_mbcnt_hi((uint32_t)(m >> 32),
           __builtin_amdgcn_mbcnt_lo((uint32_t)m, 0));
}

// ---- workspace layout (bytes) ----
#define O_XF   0
#define SZ_XF  (BATCH*64*2*64*8*4)        // 16,777,216  bf16 hi/lo fragments
#define O_SQ   (O_XF + SZ_XF)
#define SZ_SQ  (BATCH*NPTS*4)             // 262,144    per-col squared norms
#define O_KNN  (O_SQ + SZ_SQ)
#define SZ_KNN (BATCH*NPTS*KNNP*4)        // 13,631,488 knn indices (padded)
#define O_Z    (O_KNN + SZ_KNN)
#define SZ_Z   (BATCH*NPTS*CDIM*4)        // 16,777,216 aggregated features
#define WS_NEED ((size_t)(O_Z + SZ_Z))    // 47,448,064

// out[b*O+o] = beta - gamma*mean*rsqrt(var+eps)   (BN constant of pooled mean)
__global__ void gcn_init(const float* __restrict__ gamma, const float* __restrict__ beta,
                         const float* __restrict__ rmean, const float* __restrict__ rvar,
                         float* __restrict__ out) {
    int i = blockIdx.x * 256 + threadIdx.x;
    if (i < BATCH * ODIM) {
        int o = i & (ODIM - 1);
        out[i] = beta[o] - gamma[o] * rmean[o] * rsqrtf(rvar[o] + BNEPS);
    }
}

// ======================= K0: bf16 hi/lo split + MFMA-fragment swizzle + sq ==============
// First 32 blocks also write the BN-constant init of out (folds gcn_init's launch).
__global__ __launch_bounds__(256) void k0_split(const float* __restrict__ X,
                                                uint32_t* __restrict__ XF,
                                                float* __restrict__ sq,
                                                const float* __restrict__ gamma,
                                                const float* __restrict__ beta,
                                                const float* __restrict__ rmean,
                                                const float* __restrict__ rvar,
                                                float* __restrict__ out) {
    if (blockIdx.x < 32) {                           // 32*256 = 8192 = BATCH*ODIM
        int i = blockIdx.x * 256 + threadIdx.x;
        int o = i & (ODIM - 1);
        out[i] = beta[o] - gamma[o] * rmean[o] * rsqrtf(rvar[o] + BNEPS);
    }
    const int b    = blockIdx.x >> 4;
    const int t16  = (blockIdx.x & 15) * 4 + (threadIdx.x >> 6);
    const int lane = threadIdx.x & 63;
    const int n    = t16 * 16 + (lane & 15);
    const int cg   = lane >> 4;
    const float* Xb = X + (size_t)b * CDIM * NPTS;
    float s = 0.f;
    for (int ks = 0; ks < 2; ks++) {
        uint32_t hi[4], lo[4];
#pragma unroll
        for (int dj = 0; dj < 4; dj++) {
            uint32_t hw[2], lw[2];
#pragma unroll
            for (int e = 0; e < 2; e++) {
                int c = ks * 32 + cg * 8 + dj * 2 + e;
                float x = Xb[(size_t)c * NPTS + n];
                s += x * x;
                uint32_t u  = __float_as_uint(x);
                uint32_t hr = (u + 0x7FFFu + ((u >> 16) & 1u)) >> 16;   // RTNE bf16
                float    hf = __uint_as_float(hr << 16);
                uint32_t ul = __float_as_uint(x - hf);
                uint32_t lr = (ul + 0x7FFFu + ((ul >> 16) & 1u)) >> 16;
                hw[e] = hr; lw[e] = lr;
            }
            hi[dj] = hw[0] | (hw[1] << 16);
            lo[dj] = lw[0] | (lw[1] << 16);
        }
        size_t entry = ((size_t)(b * 64 + t16) * 2 + ks) * 64 + lane;
        uint32_t* p = XF + entry * 8;
        *(uint4*)p       = make_uint4(hi[0], hi[1], hi[2], hi[3]);
        *(uint4*)(p + 4) = make_uint4(lo[0], lo[1], lo[2], lo[3]);
    }
    s += __shfl_xor(s, 16, 64);
    s += __shfl_xor(s, 32, 64);
    if (lane < 16) sq[b * NPTS + n] = s;
}

// ======================= K1: MFMA Gram + 16-bit ballot-search 49-select -> knn ==========
// 512 threads (8 waves), 16 rows/block -- round-5 proven shell. Keys = top-16 bits of
// the monotone map, packed 2 rows/uint (32 KB LDS). Select: interleaved 2-row binary
// search over [wave_min, max_of_lane_mins] (~6-9 iters). Emit: ballot + v_mbcnt ranks
// with uniform skip of empty tiles (index-ascending tie-break, same set as round 5).
__global__ __launch_bounds__(512, 6) void k1_gram_select(const uint32_t* __restrict__ XF,
                                                         const float* __restrict__ sq,
                                                         int* __restrict__ knn) {
    __shared__ uint32_t s_pk[8 * 1024];              // 32 KB packed keys
    const int b    = blockIdx.x >> 6;
    const int rt   = blockIdx.x & 63;                // 16-row tile
    const int wave = threadIdx.x >> 6, lane = threadIdx.x & 63;
    const int q = lane >> 4, l15 = lane & 15;

    // A fragments (rows rt*16..+15), shared by all waves
    bf16x8 ahi[2], alo[2];
#pragma unroll
    for (int ks = 0; ks < 2; ks++) {
        const uint32_t* p = XF + (((size_t)(b * 64 + rt) * 2 + ks) * 64 + lane) * 8;
        ahi[ks] = *(const bf16x8*)p;
        alo[ks] = *(const bf16x8*)(p + 4);
    }
    const float* sqb = sq + b * NPTS;

#pragma unroll
    for (int tt = 0; tt < 8; tt++) {                 // wave's 8 col-tiles
        const int t16 = wave * 8 + tt;
        f32x4 acc = {0.f, 0.f, 0.f, 0.f};
#pragma unroll
        for (int ks = 0; ks < 2; ks++) {
            const uint32_t* p = XF + (((size_t)(b * 64 + t16) * 2 + ks) * 64 + lane) * 8;
            bf16x8 bhi = *(const bf16x8*)p;
            bf16x8 blo = *(const bf16x8*)(p + 4);
            acc = __builtin_amdgcn_mfma_f32_16x16x32_bf16(ahi[ks], bhi, acc, 0, 0, 0);
            acc = __builtin_amdgcn_mfma_f32_16x16x32_bf16(alo[ks], bhi, acc, 0, 0, 0);
            acc = __builtin_amdgcn_mfma_f32_16x16x32_bf16(ahi[ks], blo, acc, 0, 0, 0);
        }
        const int col  = t16 * 16 + l15;
        const float sqv = sqb[col];
        uint32_t k16[4];
#pragma unroll
        for (int i = 0; i < 4; i++) {
            int row = q * 4 + i;                     // C layout: row=(lane>>4)*4+reg
            float d = fmaf(-2.f, acc[i], sqv);       // sq_r dropped (row-monotone)
            if (col == rt * 16 + row) d = __uint_as_float(0x7F800000u);  // self
            uint32_t u = __float_as_uint(d);
            uint32_t key = ((int)u < 0) ? ~u : (u | 0x80000000u);
            k16[i] = key >> 16;                      // 16-bit monotone key
        }
        const int p0 = 2 * q, p1 = 2 * q + 1;        // row pairs (2-way wr conflict: free)
        s_pk[p0 * 1024 + (col ^ ((p0 & 3) << 3))] = k16[0] | (k16[1] << 16);
        s_pk[p1 * 1024 + (col ^ ((p1 & 3) << 3))] = k16[2] | (k16[3] << 16);
    }
    __syncthreads();

    // ---- load this wave's packed row-pair, unpack to 16-bit keys ----
    uint32_t k0r[16], k1r[16];
    {
        const int sw = (wave & 3) << 3;
#pragma unroll
        for (int tt = 0; tt < 16; tt++) {
            uint32_t pk = s_pk[wave * 1024 + ((tt * 64 + lane) ^ sw)];
            k0r[tt] = pk & 0xFFFFu;
            k1r[tt] = pk >> 16;
        }
    }

    // ---- narrowed bounds per row: lo = wave min, hi = max over lanes of lane-min ----
    uint32_t lo0, hi0, lo1, hi1;
    {
        uint32_t lm0 = k0r[0], lm1 = k1r[0];
#pragma unroll
        for (int tt = 1; tt < 16; tt++) {
            lm0 = k0r[tt] < lm0 ? k0r[tt] : lm0;
            lm1 = k1r[tt] < lm1 ? k1r[tt] : lm1;
        }
        uint32_t g0 = lm0, m0 = lm0, g1 = lm1, m1 = lm1;
#pragma unroll
        for (int off = 1; off < 64; off <<= 1) {
            uint32_t a0 = (uint32_t)__shfl_xor((int)g0, off, 64);
            uint32_t b0 = (uint32_t)__shfl_xor((int)m0, off, 64);
            uint32_t a1 = (uint32_t)__shfl_xor((int)g1, off, 64);
            uint32_t b1 = (uint32_t)__shfl_xor((int)m1, off, 64);
            g0 = a0 < g0 ? a0 : g0;  m0 = b0 > m0 ? b0 : m0;
            g1 = a1 < g1 ? a1 : g1;  m1 = b1 > m1 ? b1 : m1;
        }
        lo0 = g0; hi0 = m0;                          // cnt(<=m) >= 64 >= KNN
        lo1 = g1; hi1 = m1;
    }

    // ---- interleaved exact binary search (16-bit space, ~6-9 iters) ----
    for (int it = 0; it < 16; it++) {
        bool a0 = lo0 < hi0, a1 = lo1 < hi1;
        if (!a0 && !a1) break;
        uint32_t mid0 = (lo0 + hi0) >> 1;
        uint32_t mid1 = (lo1 + hi1) >> 1;
        int cnt0 = 0, cnt1 = 0;
#pragma unroll
        for (int tt = 0; tt < 16; tt++) {
            cnt0 += __popcll(__ballot(k0r[tt] <= mid0));
            cnt1 += __popcll(__ballot(k1r[tt] <= mid1));
        }
        if (a0) { if (cnt0 >= KNN) hi0 = mid0; else lo0 = mid0 + 1; }
        if (a1) { if (cnt1 >= KNN) hi1 = mid1; else lo1 = mid1 + 1; }
    }

    // ---- emit: ballot + mbcnt ranks, uniform skip of empty tiles ----
    // lt-lanes fill slots [0,total_lt), eq-lanes fill [total_lt,KNN) in ascending
    // element-index order (tt-major, lane-minor) -- identical set+order to round 5.
#pragma unroll
    for (int r = 0; r < 2; r++) {
        const int row = wave * 2 + r;
        const uint32_t vstar = r ? lo1 : lo0;
        const uint32_t* k = r ? k1r : k0r;
        int total_lt = 0;
#pragma unroll
        for (int tt = 0; tt < 16; tt++)
            total_lt += __popcll(__ballot(k[tt] < vstar));
        int base_lt = 0, base_eq = total_lt;         // total_lt <= 48 by minimality
        int* kout = knn + ((size_t)b * NPTS + rt * 16 + row) * KNNP;
#pragma unroll
        for (int tt = 0; tt < 16; tt++) {
            bool islt = k[tt] < vstar;
            bool iseq = k[tt] == vstar;
            unsigned long long mlt = __ballot(islt);
            unsigned long long meq = __ballot(iseq);
            if (mlt | meq) {                         // wave-uniform skip of empty tiles
                int pos = islt ? (base_lt + mbcnt64(mlt)) : (base_eq + mbcnt64(meq));
                if (islt || (iseq && pos < KNN)) kout[pos] = tt * 64 + lane;
            }
            base_lt += __popcll(mlt);
            base_eq += __popcll(meq);
        }
    }
}

// ======================= K2a: neighbor aggregation -> z =================================
// 512 blocks = (b, cg, half), 256 threads. lane = (row rl, ch-group g): each lane
// privately sums all 49 neighbors for its (row, 4ch) -> independent b128 gathers,
// no cross-lane reduction, no shuffles. knn int4s prefetched up front.
__global__ __launch_bounds__(256) void k2a_aggregate(const float* __restrict__ X,
                                                     const int* __restrict__ knn,
                                                     float* __restrict__ z) {
    __shared__ float XT[16 * 1024];                  // 64 KB, [n][16ch] quad-swizzled
    const int b = blockIdx.x >> 3, cg = (blockIdx.x >> 1) & 3, half = blockIdx.x & 1;
    const int t = threadIdx.x;
    const float* Xb = X + ((size_t)b * CDIM + cg * 16) * NPTS;
#pragma unroll
    for (int nn = 0; nn < 4; nn++) {                 // stage 16 ch x 1024 cols transposed
        int n = nn * 256 + t;
#pragma unroll
        for (int g = 0; g < 4; g++) {
            float4 v;
            v.x = Xb[(size_t)(4 * g + 0) * NPTS + n];
            v.y = Xb[(size_t)(4 * g + 1) * NPTS + n];
            v.z = Xb[(size_t)(4 * g + 2) * NPTS + n];
            v.w = Xb[(size_t)(4 * g + 3) * NPTS + n];
            int qp = g ^ ((n >> 1) & 3);             // full 32-bank spread for b128
            *(float4*)&XT[n * 16 + qp * 4] = v;
        }
    }
    __syncthreads();
    const int wave = t >> 6, lane = t & 63;
    const int rl = lane >> 2, g = lane & 3;          // 16 rows x 4 ch-groups per iter
    for (int rr = 0; rr < 8; rr++) {
        const int row = half * 512 + wave * 128 + rr * 16 + rl;
        const int* kr = knn + ((size_t)b * NPTS + row) * KNNP;
        int4 j[13];
#pragma unroll
        for (int c = 0; c < 13; c++) j[c] = *(const int4*)&kr[c * 4];
        float4 s = {0.f, 0.f, 0.f, 0.f};
#pragma unroll
        for (int c = 0; c < 12; c++) {               // 48 neighbors
            int js[4] = {j[c].x, j[c].y, j[c].z, j[c].w};
#pragma unroll
            for (int e = 0; e < 4; e++) {
                int jj = js[e];
                float4 v = *(const float4*)&XT[jj * 16 + ((g ^ ((jj >> 1) & 3)) << 2)];
                s.x += v.x; s.y += v.y; s.z += v.z; s.w += v.w;
            }
        }
        {                                            // neighbor 48
            int jj = j[12].x;
            float4 v = *(const float4*)&XT[jj * 16 + ((g ^ ((jj >> 1) & 3)) << 2)];
            s.x += v.x; s.y += v.y; s.z += v.z; s.w += v.w;
        }
        *(float4*)&z[((size_t)b * NPTS + row) * CDIM + cg * 16 + g * 4] = s;
    }
}

// ======================= K2b: z -> W,relu,BN,pool -> out ================================
__global__ __launch_bounds__(256) void k2b_gemm(const float* __restrict__ z,
                                                const float* __restrict__ W,
                                                const float* __restrict__ bias,
                                                const float* __restrict__ gamma,
                                                const float* __restrict__ rvar,
                                                float* __restrict__ out) {
    __shared__ __align__(16) float s_zz[128 * 64];   // 32 KB staged z tile
    __shared__ float s_red[2][256];
    const int b = blockIdx.x >> 3, nq = blockIdx.x & 7;
    const int t = threadIdx.x;
    const float* zb = z + ((size_t)b * NPTS + nq * 128) * CDIM;
#pragma unroll
    for (int qq = 0; qq < 8; qq++) {                 // coalesced float4 staging
        int e = qq * 256 + t;
        *(float4*)&s_zz[e * 4] = *(const float4*)&zb[e * 4];
    }
    __syncthreads();
    const int o2 = t & 63, h = t >> 6;               // o in {o2, o2+64}; 4 row-groups
    float4 w0[16], w1[16];
#pragma unroll
    for (int c4 = 0; c4 < 16; c4++) {
        w0[c4] = *(const float4*)&W[(size_t)o2 * CDIM + c4 * 4];
        w1[c4] = *(const float4*)&W[(size_t)(o2 + 64) * CDIM + c4 * 4];
    }
    const float b0 = bias[o2], b1 = bias[o2 + 64];
    float r0 = 0.f, r1 = 0.f;
    for (int r = 0; r < 32; r++) {
        const float* zr = &s_zz[(h * 32 + r) * 64];  // wave-uniform -> LDS broadcast
        float a0 = 0.f, a1 = 0.f;
#pragma unroll
        for (int c4 = 0; c4 < 16; c4++) {
            float4 zv = *(const float4*)&zr[c4 * 4];
            a0 += w0[c4].x * zv.x + w0[c4].y * zv.y + w0[c4].z * zv.z + w0[c4].w * zv.w;
            a1 += w1[c4].x * zv.x + w1[c4].y * zv.y + w1[c4].z * zv.z + w1[c4].w * zv.w;
        }
        r0 += fmaxf(a0 * (1.f / KNN) + b0, 0.f);
        r1 += fmaxf(a1 * (1.f / KNN) + b1, 0.f);
    }
    s_red[0][t] = r0; s_red[1][t] = r1;
    __syncthreads();
    if (t < 128) {
        const int oo = t & 63, which = t >> 6;
        const int o = which * 64 + oo;
        float sum = s_red[which][oo] + s_red[which][64 + oo] +
                    s_red[which][128 + oo] + s_red[which][192 + oo];
        float scale = gamma[o] * rsqrtf(rvar[o] + BNEPS) * (1.f / NPTS);
        atomicAdd(&out[b * ODIM + o], sum * scale);
    }
}

// ======================= Fallback: round-1 fused kernel (no workspace) ==================
#define RTILE 8
#define APAD  1028
#define WPAD  132
#define POOLF (64 * WPAD)

__global__ __launch_bounds__(256) void gcn_main(
    const float* __restrict__ X, const float* __restrict__ W,
    const float* __restrict__ bias, const float* __restrict__ gamma,
    const float* __restrict__ rvar, float* __restrict__ out)
{
    __shared__ __align__(16) float s_pool[POOLF];
    __shared__ __align__(16) float s_fstage[4][APAD];
    __shared__ int   s_knn[RTILE][KNN];
    __shared__ float s_z[RTILE][CDIM];

    const int t = threadIdx.x;
    const int b = blockIdx.x >> 7;
    const int rtile = blockIdx.x & 127;
    const int r0 = rtile * RTILE;
    const float* Xb = X + (size_t)b * CDIM * NPTS;

    float acc[RTILE][4];
    float sqv[4];
#pragma unroll
    for (int r = 0; r < RTILE; r++)
#pragma unroll
        for (int u = 0; u < 4; u++) acc[r][u] = 0.f;
#pragma unroll
    for (int u = 0; u < 4; u++) sqv[u] = 0.f;

    for (int ch = 0; ch < 16; ch++) {
        const int c0 = ch * 4;
#pragma unroll
        for (int cc = 0; cc < 4; cc++) {
            float4 v = *(const float4*)(Xb + (size_t)(c0 + cc) * NPTS + 4 * t);
            *(float4*)&s_fstage[cc][4 * t] = v;
        }
        __syncthreads();
#pragma unroll
        for (int cc = 0; cc < 4; cc++) {
            float4 bv4 = *(const float4*)&s_fstage[cc][4 * t];
            float bv[4] = {bv4.x, bv4.y, bv4.z, bv4.w};
#pragma unroll
            for (int u = 0; u < 4; u++) sqv[u] += bv[u] * bv[u];
            const float* arow = Xb + (size_t)(c0 + cc) * NPTS + r0;
            float4 a0 = *(const float4*)(arow);
            float4 a1 = *(const float4*)(arow + 4);
            float av[8] = {a0.x, a0.y, a0.z, a0.w, a1.x, a1.y, a1.z, a1.w};
#pragma unroll
            for (int r = 0; r < RTILE; r++)
#pragma unroll
                for (int u = 0; u < 4; u++) acc[r][u] += av[r] * bv[u];
        }
        __syncthreads();
    }

    float* s_dist = s_pool;
#pragma unroll
    for (int r = 0; r < RTILE; r++) {
        const int rG = r0 + r;
        float d[4];
#pragma unroll
        for (int u = 0; u < 4; u++) {
            float dd = sqv[u] - 2.f * acc[r][u];
            d[u] = (4 * t + u == rG) ? __uint_as_float(0x7F800000u) : dd;
        }
        *(float4*)&s_dist[r * NPTS + 4 * t] = make_float4(d[0], d[1], d[2], d[3]);
    }
    __syncthreads();

    const int wave = t >> 6, lane = t & 63;
    const unsigned long long ltmask = (1ull << lane) - 1ull;
    for (int rr = 0; rr < 2; rr++) {
        const int row = wave * 2 + rr;
        unsigned key[16];
#pragma unroll
        for (int tt = 0; tt < 16; tt++) {
            unsigned u = __float_as_uint(s_dist[row * NPTS + tt * 64 + lane]);
            key[tt] = (u & 0x80000000u) ? ~u : (u | 0x80000000u);
        }
        unsigned lo = 0u, hi = 0xFFFFFFFFu;
        while (lo < hi) {
            unsigned mid = lo + ((hi - lo) >> 1);
            int cnt = 0;
#pragma unroll
            for (int tt = 0; tt < 16; tt++)
                cnt += __popcll(__ballot(key[tt] <= mid));
            if (cnt >= KNN) hi = mid; else lo = mid + 1;
        }
        const unsigned v49 = lo;
        int cntless = 0;
#pragma unroll
        for (int tt = 0; tt < 16; tt++)
            cntless += __popcll(__ballot(key[tt] < v49));
        const int need = KNN - cntless;
        int base = 0, eqtaken = 0;
#pragma unroll
        for (int tt = 0; tt < 16; tt++) {
            bool islt = key[tt] < v49;
            bool iseq = key[tt] == v49;
            unsigned long long meq = __ballot(iseq);
            int eqrank = eqtaken + __popcll(meq & ltmask);
            bool sel = islt || (iseq && (eqrank < need));
            unsigned long long msel = __ballot(sel);
            if (sel) {
                int pos = base + __popcll(msel & ltmask);
                s_knn[row][pos] = tt * 64 + lane;
            }
            base    += __popcll(msel);
            eqtaken += __popcll(meq);
        }
    }
    __syncthreads();

    float* astage = s_pool;
    float* s_redf = (float*)s_fstage;
    const int ar = t >> 5, acc8 = (t & 31) >> 2, ks = t & 3;
    for (int c0 = 0; c0 < CDIM; c0 += 8) {
#pragma unroll
        for (int qq = 0; qq < 8; qq++) {
            int if4 = qq * 256 + t;
            int cc = if4 >> 8, j4 = if4 & 255;
            float4 v = *(const float4*)(Xb + (size_t)(c0 + cc) * NPTS + 4 * j4);
            *(float4*)&astage[cc * APAD + 4 * j4] = v;
        }
        __syncthreads();
        float partial = 0.f;
        for (int k = ks; k < KNN; k += 4)
            partial += astage[acc8 * APAD + s_knn[ar][k]];
        s_redf[t] = partial;
        __syncthreads();
        if (t < 64) {
            int r = t >> 3, cc = t & 7;
            int bi = r * 32 + cc * 4;
            s_z[r][c0 + cc] = s_redf[bi] + s_redf[bi + 1] + s_redf[bi + 2] + s_redf[bi + 3];
        }
        __syncthreads();
    }

    float* wt = s_pool;
#pragma unroll 4
    for (int qq = 0; qq < 32; qq++) {
        int e = qq * 256 + t;
        int o = e >> 6, c = e & 63;
        wt[c * WPAD + o] = W[e];
    }
    __syncthreads();
    const int o = t & 127, rg = t >> 7;
    float facc[4] = {0.f, 0.f, 0.f, 0.f};
    for (int c = 0; c < CDIM; c += 4) {
        float w0 = wt[(c + 0) * WPAD + o], w1 = wt[(c + 1) * WPAD + o];
        float w2 = wt[(c + 2) * WPAD + o], w3 = wt[(c + 3) * WPAD + o];
#pragma unroll
        for (int qq = 0; qq < 4; qq++) {
            float4 zv = *(const float4*)&s_z[rg * 4 + qq][c];
            facc[qq] += w0 * zv.x + w1 * zv.y + w2 * zv.z + w3 * zv.w;
        }
    }
    const float bo = bias[o];
    float rsum = 0.f;
#pragma unroll
    for (int qq = 0; qq < 4; qq++) {
        float f = facc[qq] * (1.f / KNN) + bo;
        rsum += fmaxf(f, 0.f);
    }
    s_redf[t] = rsum;
    __syncthreads();
    if (t < 128) {
        float scale = gamma[t] * rsqrtf(rvar[t] + BNEPS) * (1.f / NPTS);
        atomicAdd(&out[b * ODIM + t], (s_redf[t] + s_redf[t + 128]) * scale);
    }
}

extern "C" void kernel_launch(void* const* d_in, const int* in_sizes, int n_in,
                              void* d_out, int out_size, void* d_ws, size_t ws_size,
                              hipStream_t stream) {
    const float* X     = (const float*)d_in[0];
    const float* W     = (const float*)d_in[1];
    const float* bias  = (const float*)d_in[2];
    const float* gamma = (const float*)d_in[3];
    const float* beta  = (const float*)d_in[4];
    const float* rmean = (const float*)d_in[5];
    const float* rvar  = (const float*)d_in[6];
    float* out = (float*)d_out;

    if (ws_size >= WS_NEED) {
        uint8_t* ws = (uint8_t*)d_ws;
        uint32_t* XF  = (uint32_t*)(ws + O_XF);
        float*    sqw = (float*)(ws + O_SQ);
        int*      knn = (int*)(ws + O_KNN);
        float*    zw  = (float*)(ws + O_Z);
        k0_split<<<BATCH * 16, 256, 0, stream>>>(X, XF, sqw, gamma, beta, rmean, rvar, out);
        k1_gram_select<<<BATCH * 64, 512, 0, stream>>>(XF, sqw, knn);
        k2a_aggregate<<<BATCH * 8, 256, 0, stream>>>(X, knn, zw);
        k2b_gemm<<<BATCH * 8, 256, 0, stream>>>(zw, W, bias, gamma, rvar, out);
    } else {
        gcn_init<<<(BATCH * ODIM + 255) / 256, 256, 0, stream>>>(gamma, beta, rmean, rvar, out);
        gcn_main<<<BATCH * (NPTS / RTILE), 256, 0, stream>>>(X, W, bias, gamma, rvar, out);
    }
}